// Round 2
// baseline (1993.857 us; speedup 1.0000x reference)
//
#include <hip/hip_runtime.h>

typedef unsigned short us;
typedef us us4 __attribute__((ext_vector_type(4)));
typedef us us8 __attribute__((ext_vector_type(8)));
typedef short bf16x8 __attribute__((ext_vector_type(8)));
typedef float f32x4 __attribute__((ext_vector_type(4)));

#define DEVI static __device__ __forceinline__

// constants for this problem instance
#define BB 16
#define NN 4096
#define PP 256
#define CC 8
#define MM (BB * NN)   // 65536

DEVI float bf2f(us u) { unsigned x = ((unsigned)u) << 16; return __builtin_bit_cast(float, x); }
DEVI us f2bf(float f) {
  unsigned x = __builtin_bit_cast(unsigned, f);
  x += 0x7fffu + ((x >> 16) & 1u);   // round to nearest even
  return (us)(x >> 16);
}

DEVI void gload_lds16(const void* g, void* l) {
  __builtin_amdgcn_global_load_lds(
      (const __attribute__((address_space(1))) void*)g,
      (__attribute__((address_space(3))) void*)l, 16, 0, 0);
}

DEVI float sigf(float x) { return 1.f / (1.f + __expf(-x)); }
DEVI float tanhfast(float a) {
  float aa = fabsf(a);
  float t = 1.f - 2.f / (1.f + __expf(2.f * aa));
  return copysignf(t, a);
}

// ---------------- weight prep: fp32 -> bf16, concatenated / gate-interleaved ----
// Wg layout (shuffle-free): row R -> J16 = R>>6, gate g = (R>>4)&3, c = R&15,
// output col j = J16*16 + c. Over K=512 ([h | s]):
//   g=0 (r):  [W_ih_r | W_hh_r]   g=1 (z): [W_ih_z | W_hh_z]
//   g=2 (xn): [W_ih_n | 0]        g=3 (hn): [0 | W_hh_n]
__global__ void k_prep(const float* __restrict__ Wres,
                       const float* __restrict__ Wpar, const float* __restrict__ bpar,
                       const float* __restrict__ Wnbr, const float* __restrict__ bnbr,
                       const float* __restrict__ Wih, const float* __restrict__ Whh,
                       const float* __restrict__ bih, const float* __restrict__ bhh,
                       us* __restrict__ Wr, us* __restrict__ Wcat, float* __restrict__ bcat,
                       us* __restrict__ Wg, float* __restrict__ bg) {
  int tid = blockIdx.x * blockDim.x + threadIdx.x;
  int nth = gridDim.x * blockDim.x;
  for (int i = tid; i < 256 * 256; i += nth) Wr[i] = f2bf(Wres[i]);
  for (int i = tid; i < 256 * 512; i += nth) {
    int o = i >> 9, k = i & 511;
    float v = (k < 256) ? Wpar[o * 256 + k] : Wnbr[o * 256 + (k - 256)];
    Wcat[i] = f2bf(v);
  }
  for (int i = tid; i < 256; i += nth) bcat[i] = bpar[i] + bnbr[i];
  for (int i = tid; i < 1024 * 512; i += nth) {
    int R = i >> 9, k = i & 511;
    int g = (R >> 4) & 3, j = ((R >> 6) << 4) + (R & 15);
    float v = 0.f;
    if (g == 0)      v = (k < 256) ? Wih[j * 256 + k]         : Whh[j * 256 + (k - 256)];
    else if (g == 1) v = (k < 256) ? Wih[(256 + j) * 256 + k] : Whh[(256 + j) * 256 + (k - 256)];
    else if (g == 2) v = (k < 256) ? Wih[(512 + j) * 256 + k] : 0.f;
    else             v = (k < 256) ? 0.f                      : Whh[(512 + j) * 256 + (k - 256)];
    Wg[i] = f2bf(v);
  }
  for (int i = tid; i < 1024; i += nth) {
    int g = (i >> 4) & 3, j = ((i >> 6) << 4) + (i & 15);
    float v;
    if (g == 0)      v = bih[j] + bhh[j];
    else if (g == 1) v = bih[256 + j] + bhh[256 + j];
    else if (g == 2) v = bih[512 + j];
    else             v = bhh[512 + j];
    bg[i] = v;
  }
}

// ---------------- x fp32 -> bf16 (vectorized) ----------------
__global__ __launch_bounds__(256) void k_f2bf(const float* __restrict__ x,
                                              us* __restrict__ o, int n8) {
  int i = blockIdx.x * blockDim.x + threadIdx.x;
  if (i >= n8) return;
  const float4* p = (const float4*)x + (size_t)i * 2;
  float4 a = p[0], b = p[1];
  us8 r;
  r[0] = f2bf(a.x); r[1] = f2bf(a.y); r[2] = f2bf(a.z); r[3] = f2bf(a.w);
  r[4] = f2bf(b.x); r[5] = f2bf(b.y); r[6] = f2bf(b.z); r[7] = f2bf(b.w);
  *(us8*)(o + (size_t)i * 8) = r;
}

// ---------------- gather: A_cat = [h[parent] | avg children h] (bf16) ----------
__global__ __launch_bounds__(256)
void k_gather(const us* __restrict__ h, const int* __restrict__ par,
              const int* __restrict__ chd, const int* __restrict__ cnt,
              us* __restrict__ Acat) {
  int wid = (blockIdx.x * blockDim.x + threadIdx.x) >> 6;  // one wave per node
  int l = threadIdx.x & 63;
  int m = wid;                       // 0..MM-1
  int b = m >> 12;                   // N = 4096
  int rowP = (b << 12) + par[m];
  us4 pv = *((const us4*)(h + ((size_t)rowP << 8)) + l);
  *((us4*)(Acat + ((size_t)m << 9)) + l) = pv;
  int c = cnt[m];
  float inv = 1.f / (float)c;
  float a0 = 0.f, a1 = 0.f, a2 = 0.f, a3 = 0.f;
  const int* ch = chd + (size_t)m * CC;
  for (int i = 0; i < c; ++i) {
    int rowC = (b << 12) + ch[i];
    us4 cv = *((const us4*)(h + ((size_t)rowC << 8)) + l);
    a0 += bf2f(cv[0]); a1 += bf2f(cv[1]); a2 += bf2f(cv[2]); a3 += bf2f(cv[3]);
  }
  us4 nb;
  nb[0] = f2bf(a0 * inv); nb[1] = f2bf(a1 * inv);
  nb[2] = f2bf(a2 * inv); nb[3] = f2bf(a3 * inv);
  *((us4*)(Acat + ((size_t)m << 9) + 256) + l) = nb;
}

// ---------------- MFMA K-step with compile-time j-fragment mask ----------------
template <int JM>
DEVI void mma_step(const us* As, const us* Bs, int wr, int wc, int l,
                   f32x4 (&acc)[4][4]) {
#pragma unroll
  for (int ks = 0; ks < 2; ++ks) {
    bf16x8 af[4], bfr[4];
#pragma unroll
    for (int i = 0; i < 4; ++i) {
      int row = wr * 64 + i * 16 + (l & 15);
      int kb = ((ks * 32 + (l >> 4) * 8) * 2) ^ ((row & 7) << 4);  // swizzled read
      af[i] = *(const bf16x8*)((const char*)As + row * 128 + kb);
    }
#pragma unroll
    for (int j = 0; j < 4; ++j)
      if (JM & (1 << j)) {
        int row = wc * 64 + j * 16 + (l & 15);
        int kb = ((ks * 32 + (l >> 4) * 8) * 2) ^ ((row & 7) << 4);
        bfr[j] = *(const bf16x8*)((const char*)Bs + row * 128 + kb);
      }
#pragma unroll
    for (int i = 0; i < 4; ++i)
#pragma unroll
      for (int j = 0; j < 4; ++j)
        if (JM & (1 << j))
          acc[i][j] = __builtin_amdgcn_mfma_f32_16x16x32_bf16(af[i], bfr[j], acc[i][j], 0, 0, 0);
  }
}

// ---------------- GEMM: C = A @ Bw^T (+bias), m97-style 128x128 tile ----------
// A virtual-concat along K: k < kSplit -> A0, else A1 (both stride strideA).
// EPI 0: write bf16.  EPI 1: write bf16 + f32.  EPI 2: fused GRU epilogue
// (shuffle-free gate layout; j-fragment == gate; skips zero MFMA quadrants).
template <int EPI>
__global__ __launch_bounds__(256, 4)
void k_gemm(const us* __restrict__ A0, const us* __restrict__ A1,
            int kSplit, int strideA,
            const us* __restrict__ Bw, int kTot,
            const float* __restrict__ bias,
            us* __restrict__ outBf, float* __restrict__ outF,
            const float* __restrict__ sF, int writeF32) {
  __shared__ __align__(16) us As[128 * 64];
  __shared__ __align__(16) us Bs[128 * 64];
  int tid = threadIdx.x;
  int w = tid >> 6, l = tid & 63;
  int wr = w >> 1, wc = w & 1;
  int mBase = blockIdx.x * 128, nBase = blockIdx.y * 128;
  f32x4 acc[4][4] = {};

  for (int kt = 0; kt < kTot; kt += 64) {
    const us* aSrc; int kOff;
    if (kt < kSplit) { aSrc = A0; kOff = kt; }
    else             { aSrc = A1; kOff = kt - kSplit; }
#pragma unroll
    for (int c = 0; c < 4; ++c) {
      int row = c * 32 + w * 8 + (l >> 3);
      int kb = ((l & 7) * 16) ^ ((row & 7) << 4);   // pre-swizzled global source
      const char* ga = (const char*)(aSrc + (size_t)(mBase + row) * strideA + kOff) + kb;
      gload_lds16(ga, (char*)As + row * 128 + (l & 7) * 16);
      const char* gb = (const char*)(Bw + (size_t)(nBase + row) * kTot + kt) + kb;
      gload_lds16(gb, (char*)Bs + row * 128 + (l & 7) * 16);
    }
    asm volatile("s_waitcnt vmcnt(0)" ::: "memory");
    __syncthreads();
    if (EPI == 2) {
      if (kt < kSplit) mma_step<0b0111>(As, Bs, wr, wc, l, acc);  // skip hn (j=3)
      else             mma_step<0b1011>(As, Bs, wr, wc, l, acc);  // skip xn (j=2)
    } else {
      mma_step<0b1111>(As, Bs, wr, wc, l, acc);
    }
    __syncthreads();
  }

  int rBase0 = mBase + wr * 64;
  int cBase0 = nBase + wc * 64;
  if (EPI == 0 || EPI == 1) {
#pragma unroll
    for (int i = 0; i < 4; ++i)
#pragma unroll
      for (int j = 0; j < 4; ++j) {
        int col = cBase0 + j * 16 + (l & 15);
        int row0 = rBase0 + i * 16 + ((l >> 4) << 2);
        float bb = bias[col];
#pragma unroll
        for (int e = 0; e < 4; ++e) {
          float v = acc[i][j][e] + bb;
          size_t off = (size_t)(row0 + e) * 256 + col;
          outBf[off] = f2bf(v);
          if (EPI == 1) outF[off] = v;
        }
      }
  } else {
    // shuffle-free: j-fragment == gate, same lane & register for all 4 gates
    int outCol = ((cBase0 >> 6) << 4) + (l & 15);
    float b0 = bias[cBase0 + 0  + (l & 15)];
    float b1 = bias[cBase0 + 16 + (l & 15)];
    float b2 = bias[cBase0 + 32 + (l & 15)];
    float b3 = bias[cBase0 + 48 + (l & 15)];
#pragma unroll
    for (int i = 0; i < 4; ++i) {
      int row0 = rBase0 + i * 16 + ((l >> 4) << 2);
#pragma unroll
      for (int e = 0; e < 4; ++e) {
        float r = sigf(acc[i][0][e] + b0);
        float z = sigf(acc[i][1][e] + b1);
        float n = tanhfast(acc[i][2][e] + b2 + r * (acc[i][3][e] + b3));
        size_t off = (size_t)(row0 + e) * 256 + outCol;
        float sv = sF[off];
        float o = (1.f - z) * n + z * sv;
        if (writeF32) outF[off] = o;
        else          outBf[off] = f2bf(o);
      }
    }
  }
}

extern "C" void kernel_launch(void* const* d_in, const int* in_sizes, int n_in,
                              void* d_out, int out_size, void* d_ws, size_t ws_size,
                              hipStream_t stream) {
  const float* x    = (const float*)d_in[0];
  const int*   par  = (const int*)d_in[1];
  const int*   chd  = (const int*)d_in[2];
  const int*   cnt  = (const int*)d_in[3];
  const float* Wres = (const float*)d_in[4];
  const float* bres = (const float*)d_in[5];
  const float* Wpar = (const float*)d_in[6];
  const float* bpar = (const float*)d_in[7];
  const float* Wnbr = (const float*)d_in[8];
  const float* bnbr = (const float*)d_in[9];
  const float* Wih  = (const float*)d_in[10];
  const float* Whh  = (const float*)d_in[11];
  const float* bih  = (const float*)d_in[12];
  const float* bhh  = (const float*)d_in[13];

  char* ws = (char*)d_ws;
  size_t off = 0;
  auto alloc = [&](size_t sz) { char* p = ws + off; off += (sz + 255) & ~(size_t)255; return p; };
  us*    Wg   = (us*)alloc((size_t)1024 * 512 * 2);
  us*    Wcat = (us*)alloc((size_t)256 * 512 * 2);
  us*    Wr   = (us*)alloc((size_t)256 * 256 * 2);
  float* bcat = (float*)alloc(256 * 4);
  float* bg   = (float*)alloc(1024 * 4);
  us*    xbf  = (us*)alloc((size_t)MM * 256 * 2);  // reused as s_bf after resize
  us*    h0   = (us*)alloc((size_t)MM * 256 * 2);
  us*    h1   = (us*)alloc((size_t)MM * 256 * 2);
  us*    Acat = (us*)alloc((size_t)MM * 512 * 2);
  us*    sbf  = xbf;
  float* sF   = (float*)d_out;  // s_f32 scratch lives in d_out (overwritten at end)

  k_prep<<<256, 256, 0, stream>>>(Wres, Wpar, bpar, Wnbr, bnbr, Wih, Whh, bih, bhh,
                                  Wr, Wcat, bcat, Wg, bg);
  k_f2bf<<<(MM * 256 / 8) / 256, 256, 0, stream>>>(x, xbf, MM * 256 / 8);

  // h0 = x @ W_resize^T + b_resize
  k_gemm<0><<<dim3(MM / 128, 2), 256, 0, stream>>>(
      xbf, xbf, 256, 256, Wr, 256, bres, h0, nullptr, nullptr, 0);

  us* hc = h0;
  for (int it = 0; it < 3; ++it) {
    us* hn = (hc == h0) ? h1 : h0;
    k_gather<<<MM / 4, 256, 0, stream>>>(hc, par, chd, cnt, Acat);
    // s = [p|m] @ Wcat^T + bcat  -> s_bf + s_f32(in d_out)
    k_gemm<1><<<dim3(MM / 128, 2), 256, 0, stream>>>(
        Acat, Acat, 512, 512, Wcat, 512, bcat, sbf, sF, nullptr, 0);
    // fused GRU: [h|s] @ Wg^T, gate epilogue -> h_next (bf16) or d_out (f32, last)
    k_gemm<2><<<dim3(MM / 128, 8), 256, 0, stream>>>(
        hc, sbf, 256, 256, Wg, 512, bg, hn, (float*)d_out, sF, (it == 2) ? 1 : 0);
    hc = hn;
  }
}

// Round 3
// 707.857 us; speedup vs baseline: 2.8168x; 2.8168x over previous
//
#include <hip/hip_runtime.h>

typedef unsigned short us;
typedef us us4 __attribute__((ext_vector_type(4)));
typedef us us8 __attribute__((ext_vector_type(8)));
typedef short bf16x8 __attribute__((ext_vector_type(8)));
typedef float f32x4 __attribute__((ext_vector_type(4)));

#define DEVI static __device__ __forceinline__

// constants for this problem instance
#define BB 16
#define NN 4096
#define PP 256
#define CC 8
#define MM (BB * NN)   // 65536

DEVI float bf2f(us u) { unsigned x = ((unsigned)u) << 16; return __builtin_bit_cast(float, x); }
DEVI us f2bf(float f) {
  unsigned x = __builtin_bit_cast(unsigned, f);
  x += 0x7fffu + ((x >> 16) & 1u);   // round to nearest even
  return (us)(x >> 16);
}

DEVI void gload_lds16(const void* g, void* l) {
  __builtin_amdgcn_global_load_lds(
      (const __attribute__((address_space(1))) void*)g,
      (__attribute__((address_space(3))) void*)l, 16, 0, 0);
}

DEVI float sigf(float x) { return 1.f / (1.f + __expf(-x)); }
DEVI float tanhfast(float a) {
  float aa = fabsf(a);
  float t = 1.f - 2.f / (1.f + __expf(2.f * aa));
  return copysignf(t, a);
}

// ---------------- weight prep: fp32 -> bf16, concatenated / gate-interleaved ----
// Wg layout (shuffle-free): row R -> J16 = R>>6, gate g = (R>>4)&3, c = R&15,
// output col j = J16*16 + c. Over K=512 ([h | s]):
//   g=0 (r):  [W_ih_r | W_hh_r]   g=1 (z): [W_ih_z | W_hh_z]
//   g=2 (xn): [W_ih_n | 0]        g=3 (hn): [0 | W_hh_n]
__global__ void k_prep(const float* __restrict__ Wres,
                       const float* __restrict__ Wpar, const float* __restrict__ bpar,
                       const float* __restrict__ Wnbr, const float* __restrict__ bnbr,
                       const float* __restrict__ Wih, const float* __restrict__ Whh,
                       const float* __restrict__ bih, const float* __restrict__ bhh,
                       us* __restrict__ Wr, us* __restrict__ Wcat, float* __restrict__ bcat,
                       us* __restrict__ Wg, float* __restrict__ bg) {
  int tid = blockIdx.x * blockDim.x + threadIdx.x;
  int nth = gridDim.x * blockDim.x;
  for (int i = tid; i < 256 * 256; i += nth) Wr[i] = f2bf(Wres[i]);
  for (int i = tid; i < 256 * 512; i += nth) {
    int o = i >> 9, k = i & 511;
    float v = (k < 256) ? Wpar[o * 256 + k] : Wnbr[o * 256 + (k - 256)];
    Wcat[i] = f2bf(v);
  }
  for (int i = tid; i < 256; i += nth) bcat[i] = bpar[i] + bnbr[i];
  for (int i = tid; i < 1024 * 512; i += nth) {
    int R = i >> 9, k = i & 511;
    int g = (R >> 4) & 3, j = ((R >> 6) << 4) + (R & 15);
    float v = 0.f;
    if (g == 0)      v = (k < 256) ? Wih[j * 256 + k]         : Whh[j * 256 + (k - 256)];
    else if (g == 1) v = (k < 256) ? Wih[(256 + j) * 256 + k] : Whh[(256 + j) * 256 + (k - 256)];
    else if (g == 2) v = (k < 256) ? Wih[(512 + j) * 256 + k] : 0.f;
    else             v = (k < 256) ? 0.f                      : Whh[(512 + j) * 256 + (k - 256)];
    Wg[i] = f2bf(v);
  }
  for (int i = tid; i < 1024; i += nth) {
    int g = (i >> 4) & 3, j = ((i >> 6) << 4) + (i & 15);
    float v;
    if (g == 0)      v = bih[j] + bhh[j];
    else if (g == 1) v = bih[256 + j] + bhh[256 + j];
    else if (g == 2) v = bih[512 + j];
    else             v = bhh[512 + j];
    bg[i] = v;
  }
}

// ---------------- x fp32 -> bf16 (vectorized) ----------------
__global__ __launch_bounds__(256) void k_f2bf(const float* __restrict__ x,
                                              us* __restrict__ o, int n8) {
  int i = blockIdx.x * blockDim.x + threadIdx.x;
  if (i >= n8) return;
  const float4* p = (const float4*)x + (size_t)i * 2;
  float4 a = p[0], b = p[1];
  us8 r;
  r[0] = f2bf(a.x); r[1] = f2bf(a.y); r[2] = f2bf(a.z); r[3] = f2bf(a.w);
  r[4] = f2bf(b.x); r[5] = f2bf(b.y); r[6] = f2bf(b.z); r[7] = f2bf(b.w);
  *(us8*)(o + (size_t)i * 8) = r;
}

// ---------------- gather: A_cat = [h[parent] | avg children h] (bf16) ----------
__global__ __launch_bounds__(256)
void k_gather(const us* __restrict__ h, const int* __restrict__ par,
              const int* __restrict__ chd, const int* __restrict__ cnt,
              us* __restrict__ Acat) {
  int wid = (blockIdx.x * blockDim.x + threadIdx.x) >> 6;  // one wave per node
  int l = threadIdx.x & 63;
  int m = wid;                       // 0..MM-1
  int b = m >> 12;                   // N = 4096
  int rowP = (b << 12) + par[m];
  us4 pv = *((const us4*)(h + ((size_t)rowP << 8)) + l);
  *((us4*)(Acat + ((size_t)m << 9)) + l) = pv;
  int c = cnt[m];
  float inv = 1.f / (float)c;
  float a0 = 0.f, a1 = 0.f, a2 = 0.f, a3 = 0.f;
  const int* ch = chd + (size_t)m * CC;
  for (int i = 0; i < c; ++i) {
    int rowC = (b << 12) + ch[i];
    us4 cv = *((const us4*)(h + ((size_t)rowC << 8)) + l);
    a0 += bf2f(cv[0]); a1 += bf2f(cv[1]); a2 += bf2f(cv[2]); a3 += bf2f(cv[3]);
  }
  us4 nb;
  nb[0] = f2bf(a0 * inv); nb[1] = f2bf(a1 * inv);
  nb[2] = f2bf(a2 * inv); nb[3] = f2bf(a3 * inv);
  *((us4*)(Acat + ((size_t)m << 9) + 256) + l) = nb;
}

// ---------------- MFMA K-step with compile-time j-fragment mask ----------------
template <int JM>
DEVI void mma_step(const us* As, const us* Bs, int wr, int wc, int l,
                   f32x4 (&acc)[4][4]) {
#pragma unroll
  for (int ks = 0; ks < 2; ++ks) {
    bf16x8 af[4], bfr[4];
#pragma unroll
    for (int i = 0; i < 4; ++i) {
      int row = wr * 64 + i * 16 + (l & 15);
      int kb = ((ks * 32 + (l >> 4) * 8) * 2) ^ ((row & 7) << 4);  // swizzled read
      af[i] = *(const bf16x8*)((const char*)As + row * 128 + kb);
    }
#pragma unroll
    for (int j = 0; j < 4; ++j)
      if (JM & (1 << j)) {
        int row = wc * 64 + j * 16 + (l & 15);
        int kb = ((ks * 32 + (l >> 4) * 8) * 2) ^ ((row & 7) << 4);
        bfr[j] = *(const bf16x8*)((const char*)Bs + row * 128 + kb);
      }
#pragma unroll
    for (int i = 0; i < 4; ++i)
#pragma unroll
      for (int j = 0; j < 4; ++j)
        if (JM & (1 << j))
          acc[i][j] = __builtin_amdgcn_mfma_f32_16x16x32_bf16(af[i], bfr[j], acc[i][j], 0, 0, 0);
  }
}

// ---------------- GEMM: C = A @ Bw^T (+bias), m97-style 128x128 tile ----------
// A virtual-concat along K: k < kSplit -> A0, else A1 (both stride strideA).
// EPI 0: write bf16.  EPI 1: write bf16 + f32.  EPI 2: fused GRU epilogue
// (shuffle-free gate layout; j-fragment == gate; skips zero MFMA quadrants).
// NOTE: launch_bounds min-waves MUST stay 2 — at 4 the unified VGPR+AGPR
// budget (128) is below the kernel's ~130 regs -> scratch spill -> 2.4 GB/dispatch
// HBM traffic and 3x slowdown (measured round 2).
template <int EPI>
__global__ __launch_bounds__(256, 2)
void k_gemm(const us* __restrict__ A0, const us* __restrict__ A1,
            int kSplit, int strideA,
            const us* __restrict__ Bw, int kTot,
            const float* __restrict__ bias,
            us* __restrict__ outBf, float* __restrict__ outF,
            const float* __restrict__ sF, int writeF32) {
  __shared__ __align__(16) us As[128 * 64];
  __shared__ __align__(16) us Bs[128 * 64];
  int tid = threadIdx.x;
  int w = tid >> 6, l = tid & 63;
  int wr = w >> 1, wc = w & 1;
  int mBase = blockIdx.x * 128, nBase = blockIdx.y * 128;
  f32x4 acc[4][4] = {};

  for (int kt = 0; kt < kTot; kt += 64) {
    const us* aSrc; int kOff;
    if (kt < kSplit) { aSrc = A0; kOff = kt; }
    else             { aSrc = A1; kOff = kt - kSplit; }
#pragma unroll
    for (int c = 0; c < 4; ++c) {
      int row = c * 32 + w * 8 + (l >> 3);
      int kb = ((l & 7) * 16) ^ ((row & 7) << 4);   // pre-swizzled global source
      const char* ga = (const char*)(aSrc + (size_t)(mBase + row) * strideA + kOff) + kb;
      gload_lds16(ga, (char*)As + row * 128 + (l & 7) * 16);
      const char* gb = (const char*)(Bw + (size_t)(nBase + row) * kTot + kt) + kb;
      gload_lds16(gb, (char*)Bs + row * 128 + (l & 7) * 16);
    }
    asm volatile("s_waitcnt vmcnt(0)" ::: "memory");
    __syncthreads();
    if (EPI == 2) {
      if (kt < kSplit) mma_step<0b0111>(As, Bs, wr, wc, l, acc);  // skip hn (j=3)
      else             mma_step<0b1011>(As, Bs, wr, wc, l, acc);  // skip xn (j=2)
    } else {
      mma_step<0b1111>(As, Bs, wr, wc, l, acc);
    }
    __syncthreads();
  }

  int rBase0 = mBase + wr * 64;
  int cBase0 = nBase + wc * 64;
  if (EPI == 0 || EPI == 1) {
#pragma unroll
    for (int i = 0; i < 4; ++i)
#pragma unroll
      for (int j = 0; j < 4; ++j) {
        int col = cBase0 + j * 16 + (l & 15);
        int row0 = rBase0 + i * 16 + ((l >> 4) << 2);
        float bb = bias[col];
#pragma unroll
        for (int e = 0; e < 4; ++e) {
          float v = acc[i][j][e] + bb;
          size_t off = (size_t)(row0 + e) * 256 + col;
          outBf[off] = f2bf(v);
          if (EPI == 1) outF[off] = v;
        }
      }
  } else {
    // shuffle-free: j-fragment == gate, same lane & register for all 4 gates
    int outCol = ((cBase0 >> 6) << 4) + (l & 15);
    float b0 = bias[cBase0 + 0  + (l & 15)];
    float b1 = bias[cBase0 + 16 + (l & 15)];
    float b2 = bias[cBase0 + 32 + (l & 15)];
    float b3 = bias[cBase0 + 48 + (l & 15)];
#pragma unroll
    for (int i = 0; i < 4; ++i) {
      int row0 = rBase0 + i * 16 + ((l >> 4) << 2);
#pragma unroll
      for (int e = 0; e < 4; ++e) {
        float r = sigf(acc[i][0][e] + b0);
        float z = sigf(acc[i][1][e] + b1);
        float n = tanhfast(acc[i][2][e] + b2 + r * (acc[i][3][e] + b3));
        size_t off = (size_t)(row0 + e) * 256 + outCol;
        float sv = sF[off];
        float o = (1.f - z) * n + z * sv;
        if (writeF32) outF[off] = o;
        else          outBf[off] = f2bf(o);
      }
    }
  }
}

extern "C" void kernel_launch(void* const* d_in, const int* in_sizes, int n_in,
                              void* d_out, int out_size, void* d_ws, size_t ws_size,
                              hipStream_t stream) {
  const float* x    = (const float*)d_in[0];
  const int*   par  = (const int*)d_in[1];
  const int*   chd  = (const int*)d_in[2];
  const int*   cnt  = (const int*)d_in[3];
  const float* Wres = (const float*)d_in[4];
  const float* bres = (const float*)d_in[5];
  const float* Wpar = (const float*)d_in[6];
  const float* bpar = (const float*)d_in[7];
  const float* Wnbr = (const float*)d_in[8];
  const float* bnbr = (const float*)d_in[9];
  const float* Wih  = (const float*)d_in[10];
  const float* Whh  = (const float*)d_in[11];
  const float* bih  = (const float*)d_in[12];
  const float* bhh  = (const float*)d_in[13];

  char* ws = (char*)d_ws;
  size_t off = 0;
  auto alloc = [&](size_t sz) { char* p = ws + off; off += (sz + 255) & ~(size_t)255; return p; };
  us*    Wg   = (us*)alloc((size_t)1024 * 512 * 2);
  us*    Wcat = (us*)alloc((size_t)256 * 512 * 2);
  us*    Wr   = (us*)alloc((size_t)256 * 256 * 2);
  float* bcat = (float*)alloc(256 * 4);
  float* bg   = (float*)alloc(1024 * 4);
  us*    xbf  = (us*)alloc((size_t)MM * 256 * 2);  // reused as s_bf after resize
  us*    h0   = (us*)alloc((size_t)MM * 256 * 2);
  us*    h1   = (us*)alloc((size_t)MM * 256 * 2);
  us*    Acat = (us*)alloc((size_t)MM * 512 * 2);
  us*    sbf  = xbf;
  float* sF   = (float*)d_out;  // s_f32 scratch lives in d_out (overwritten at end)

  k_prep<<<256, 256, 0, stream>>>(Wres, Wpar, bpar, Wnbr, bnbr, Wih, Whh, bih, bhh,
                                  Wr, Wcat, bcat, Wg, bg);
  k_f2bf<<<(MM * 256 / 8) / 256, 256, 0, stream>>>(x, xbf, MM * 256 / 8);

  // h0 = x @ W_resize^T + b_resize
  k_gemm<0><<<dim3(MM / 128, 2), 256, 0, stream>>>(
      xbf, xbf, 256, 256, Wr, 256, bres, h0, nullptr, nullptr, 0);

  us* hc = h0;
  for (int it = 0; it < 3; ++it) {
    us* hn = (hc == h0) ? h1 : h0;
    k_gather<<<MM / 4, 256, 0, stream>>>(hc, par, chd, cnt, Acat);
    // s = [p|m] @ Wcat^T + bcat  -> s_bf + s_f32(in d_out)
    k_gemm<1><<<dim3(MM / 128, 2), 256, 0, stream>>>(
        Acat, Acat, 512, 512, Wcat, 512, bcat, sbf, sF, nullptr, 0);
    // fused GRU: [h|s] @ Wg^T, gate epilogue -> h_next (bf16) or d_out (f32, last)
    k_gemm<2><<<dim3(MM / 128, 8), 256, 0, stream>>>(
        hc, sbf, 256, 256, Wg, 512, bg, hn, (float*)d_out, sF, (it == 2) ? 1 : 0);
    hc = hn;
  }
}

// Round 4
// 617.092 us; speedup vs baseline: 3.2311x; 1.1471x over previous
//
#include <hip/hip_runtime.h>

typedef unsigned short us;
typedef us us4 __attribute__((ext_vector_type(4)));
typedef us us8 __attribute__((ext_vector_type(8)));
typedef short bf16x8 __attribute__((ext_vector_type(8)));
typedef float f32x4 __attribute__((ext_vector_type(4)));

#define DEVI static __device__ __forceinline__

// constants for this problem instance
#define BB 16
#define NN 4096
#define PP 256
#define CC 8
#define MM (BB * NN)   // 65536

DEVI float bf2f(us u) { unsigned x = ((unsigned)u) << 16; return __builtin_bit_cast(float, x); }
DEVI us f2bf(float f) {
  unsigned x = __builtin_bit_cast(unsigned, f);
  x += 0x7fffu + ((x >> 16) & 1u);   // round to nearest even
  return (us)(x >> 16);
}

DEVI void gload_lds16(const void* g, void* l) {
  __builtin_amdgcn_global_load_lds(
      (const __attribute__((address_space(1))) void*)g,
      (__attribute__((address_space(3))) void*)l, 16, 0, 0);
}

DEVI float sigf(float x) { return 1.f / (1.f + __expf(-x)); }
DEVI float tanhfast(float a) {
  float aa = fabsf(a);
  float t = 1.f - 2.f / (1.f + __expf(2.f * aa));
  return copysignf(t, a);
}

// ---------------- weight prep: fp32 -> bf16, concatenated / gate-interleaved ----
// Wg layout (shuffle-free): row R -> J16 = R>>6, gate g = (R>>4)&3, c = R&15,
// output col j = J16*16 + c. Over K=512 ([h | s]):
//   g=0 (r):  [W_ih_r | W_hh_r]   g=1 (z): [W_ih_z | W_hh_z]
//   g=2 (xn): [W_ih_n | 0]        g=3 (hn): [0 | W_hh_n]
__global__ void k_prep(const float* __restrict__ Wres,
                       const float* __restrict__ Wpar, const float* __restrict__ bpar,
                       const float* __restrict__ Wnbr, const float* __restrict__ bnbr,
                       const float* __restrict__ Wih, const float* __restrict__ Whh,
                       const float* __restrict__ bih, const float* __restrict__ bhh,
                       us* __restrict__ Wr, us* __restrict__ Wcat, float* __restrict__ bcat,
                       us* __restrict__ Wg, float* __restrict__ bg) {
  int tid = blockIdx.x * blockDim.x + threadIdx.x;
  int nth = gridDim.x * blockDim.x;
  for (int i = tid; i < 256 * 256; i += nth) Wr[i] = f2bf(Wres[i]);
  for (int i = tid; i < 256 * 512; i += nth) {
    int o = i >> 9, k = i & 511;
    float v = (k < 256) ? Wpar[o * 256 + k] : Wnbr[o * 256 + (k - 256)];
    Wcat[i] = f2bf(v);
  }
  for (int i = tid; i < 256; i += nth) bcat[i] = bpar[i] + bnbr[i];
  for (int i = tid; i < 1024 * 512; i += nth) {
    int R = i >> 9, k = i & 511;
    int g = (R >> 4) & 3, j = ((R >> 6) << 4) + (R & 15);
    float v = 0.f;
    if (g == 0)      v = (k < 256) ? Wih[j * 256 + k]         : Whh[j * 256 + (k - 256)];
    else if (g == 1) v = (k < 256) ? Wih[(256 + j) * 256 + k] : Whh[(256 + j) * 256 + (k - 256)];
    else if (g == 2) v = (k < 256) ? Wih[(512 + j) * 256 + k] : 0.f;
    else             v = (k < 256) ? 0.f                      : Whh[(512 + j) * 256 + (k - 256)];
    Wg[i] = f2bf(v);
  }
  for (int i = tid; i < 1024; i += nth) {
    int g = (i >> 4) & 3, j = ((i >> 6) << 4) + (i & 15);
    float v;
    if (g == 0)      v = bih[j] + bhh[j];
    else if (g == 1) v = bih[256 + j] + bhh[256 + j];
    else if (g == 2) v = bih[512 + j];
    else             v = bhh[512 + j];
    bg[i] = v;
  }
}

// ---------------- x fp32 -> bf16 (vectorized) ----------------
__global__ __launch_bounds__(256) void k_f2bf(const float* __restrict__ x,
                                              us* __restrict__ o, int n8) {
  int i = blockIdx.x * blockDim.x + threadIdx.x;
  if (i >= n8) return;
  const float4* p = (const float4*)x + (size_t)i * 2;
  float4 a = p[0], b = p[1];
  us8 r;
  r[0] = f2bf(a.x); r[1] = f2bf(a.y); r[2] = f2bf(a.z); r[3] = f2bf(a.w);
  r[4] = f2bf(b.x); r[5] = f2bf(b.y); r[6] = f2bf(b.z); r[7] = f2bf(b.w);
  *(us8*)(o + (size_t)i * 8) = r;
}

// ---------------- gather: A_cat = [h[parent] | avg children h] (bf16) ----------
// All 8 child rows loaded unconditionally (indices always valid) so the loads
// issue in one latency window; contribution masked by count.
__global__ __launch_bounds__(256)
void k_gather(const us* __restrict__ h, const int* __restrict__ par,
              const int* __restrict__ chd, const int* __restrict__ cnt,
              us* __restrict__ Acat) {
  int wid = (blockIdx.x * blockDim.x + threadIdx.x) >> 6;  // one wave per node
  int l = threadIdx.x & 63;
  int m = wid;                       // 0..MM-1
  int b = m >> 12;                   // N = 4096
  int rowP = (b << 12) + par[m];
  us4 pv = *((const us4*)(h + ((size_t)rowP << 8)) + l);
  *((us4*)(Acat + ((size_t)m << 9)) + l) = pv;
  int c = cnt[m];
  float inv = 1.f / (float)c;
  const int* ch = chd + (size_t)m * CC;
  us4 cv[CC];
#pragma unroll
  for (int i = 0; i < CC; ++i) {
    int rowC = (b << 12) + ch[i];
    cv[i] = *((const us4*)(h + ((size_t)rowC << 8)) + l);
  }
  float a0 = 0.f, a1 = 0.f, a2 = 0.f, a3 = 0.f;
#pragma unroll
  for (int i = 0; i < CC; ++i) {
    float wgt = (i < c) ? 1.f : 0.f;
    a0 += wgt * bf2f(cv[i][0]); a1 += wgt * bf2f(cv[i][1]);
    a2 += wgt * bf2f(cv[i][2]); a3 += wgt * bf2f(cv[i][3]);
  }
  us4 nb;
  nb[0] = f2bf(a0 * inv); nb[1] = f2bf(a1 * inv);
  nb[2] = f2bf(a2 * inv); nb[3] = f2bf(a3 * inv);
  *((us4*)(Acat + ((size_t)m << 9) + 256) + l) = nb;
}

// ---------------- MFMA K-step with compile-time j-fragment mask ----------------
template <int JM>
DEVI void mma_step(const us* As, const us* Bs, int wr, int wc, int l,
                   f32x4 (&acc)[4][4]) {
#pragma unroll
  for (int ks = 0; ks < 2; ++ks) {
    bf16x8 af[4], bfr[4];
#pragma unroll
    for (int i = 0; i < 4; ++i) {
      int row = wr * 64 + i * 16 + (l & 15);
      int kb = ((ks * 32 + (l >> 4) * 8) * 2) ^ ((row & 7) << 4);  // swizzled read
      af[i] = *(const bf16x8*)((const char*)As + row * 128 + kb);
    }
#pragma unroll
    for (int j = 0; j < 4; ++j)
      if (JM & (1 << j)) {
        int row = wc * 64 + j * 16 + (l & 15);
        int kb = ((ks * 32 + (l >> 4) * 8) * 2) ^ ((row & 7) << 4);
        bfr[j] = *(const bf16x8*)((const char*)Bs + row * 128 + kb);
      }
#pragma unroll
    for (int i = 0; i < 4; ++i)
#pragma unroll
      for (int j = 0; j < 4; ++j)
        if (JM & (1 << j))
          acc[i][j] = __builtin_amdgcn_mfma_f32_16x16x32_bf16(af[i], bfr[j], acc[i][j], 0, 0, 0);
  }
}

// ---------------- GEMM: C = A @ Bw^T (+bias), 128x128 tile, dbuf prefetch ------
// Flat 1-D grid of (NM*nTiles) blocks, XCD-chunked: g=(bid&7)*NB/8+(bid>>3),
// m=g/nTiles, n=g%nTiles -> A-panel sharers run back-to-back on one XCD (L2 hit).
// K-loop: stage(next tile) -> vmcnt(8) (counted; only drain on last) -> barrier
// -> MFMA from current -> barrier. LDS 64 KB (2 bufs), 2 blocks/CU (reg-limited).
// NOTE: launch_bounds min-waves MUST stay 2 (VGPR 112 + AGPR 64; at 4 it spills
// -> 2.4 GB/dispatch scratch traffic, 3x slowdown — measured round 2).
template <int EPI>
__global__ __launch_bounds__(256, 2)
void k_gemm(const us* __restrict__ A0, const us* __restrict__ A1,
            int kSplit, int strideA,
            const us* __restrict__ Bw, int kTot,
            const float* __restrict__ bias,
            us* __restrict__ outBf, float* __restrict__ outF,
            const float* __restrict__ sF, int writeF32, int nTiles) {
  __shared__ __align__(16) us As[2][128 * 64];
  __shared__ __align__(16) us Bs[2][128 * 64];
  int tid = threadIdx.x;
  int w = tid >> 6, l = tid & 63;
  int wr = w >> 1, wc = w & 1;
  int bid = blockIdx.x;
  int per = gridDim.x >> 3;
  int g = (bid & 7) * per + (bid >> 3);
  int mi = g / nTiles, ni = g - mi * nTiles;
  int mBase = mi * 128, nBase = ni * 128;
  f32x4 acc[4][4] = {};

  auto stage = [&](int t) {
    int kt = t * 64, buf = t & 1;
    const us* aSrc; int kOff;
    if (kt < kSplit) { aSrc = A0; kOff = kt; }
    else             { aSrc = A1; kOff = kt - kSplit; }
#pragma unroll
    for (int c = 0; c < 4; ++c) {
      int row = c * 32 + w * 8 + (l >> 3);
      int kb = ((l & 7) * 16) ^ ((row & 7) << 4);   // pre-swizzled global source
      const char* ga = (const char*)(aSrc + (size_t)(mBase + row) * strideA + kOff) + kb;
      gload_lds16(ga, (char*)As[buf] + row * 128 + (l & 7) * 16);
      const char* gb = (const char*)(Bw + (size_t)(nBase + row) * kTot + kt) + kb;
      gload_lds16(gb, (char*)Bs[buf] + row * 128 + (l & 7) * 16);
    }
  };

  int nkt = kTot >> 6;
  stage(0);
  for (int t = 0; t < nkt; ++t) {
    if (t + 1 < nkt) {
      stage(t + 1);
      asm volatile("s_waitcnt vmcnt(8)" ::: "memory");  // current tile's 8 done
    } else {
      asm volatile("s_waitcnt vmcnt(0)" ::: "memory");
    }
    __syncthreads();
    int buf = t & 1;
    if (EPI == 2) {
      if (t * 64 < kSplit) mma_step<0b0111>(As[buf], Bs[buf], wr, wc, l, acc);  // skip hn
      else                 mma_step<0b1011>(As[buf], Bs[buf], wr, wc, l, acc);  // skip xn
    } else {
      mma_step<0b1111>(As[buf], Bs[buf], wr, wc, l, acc);
    }
    __syncthreads();   // all waves done with buf before it is re-staged
  }

  int rBase0 = mBase + wr * 64;
  int cBase0 = nBase + wc * 64;
  if (EPI == 0 || EPI == 1) {
#pragma unroll
    for (int i = 0; i < 4; ++i)
#pragma unroll
      for (int j = 0; j < 4; ++j) {
        int col = cBase0 + j * 16 + (l & 15);
        int row0 = rBase0 + i * 16 + ((l >> 4) << 2);
        float bb = bias[col];
#pragma unroll
        for (int e = 0; e < 4; ++e) {
          float v = acc[i][j][e] + bb;
          size_t off = (size_t)(row0 + e) * 256 + col;
          outBf[off] = f2bf(v);
          if (EPI == 1) outF[off] = v;
        }
      }
  } else {
    // shuffle-free: j-fragment == gate, same lane & register for all 4 gates
    int outCol = ((cBase0 >> 6) << 4) + (l & 15);
    float b0 = bias[cBase0 + 0  + (l & 15)];
    float b1 = bias[cBase0 + 16 + (l & 15)];
    float b2 = bias[cBase0 + 32 + (l & 15)];
    float b3 = bias[cBase0 + 48 + (l & 15)];
#pragma unroll
    for (int i = 0; i < 4; ++i) {
      int row0 = rBase0 + i * 16 + ((l >> 4) << 2);
#pragma unroll
      for (int e = 0; e < 4; ++e) {
        float r = sigf(acc[i][0][e] + b0);
        float z = sigf(acc[i][1][e] + b1);
        float n = tanhfast(acc[i][2][e] + b2 + r * (acc[i][3][e] + b3));
        size_t off = (size_t)(row0 + e) * 256 + outCol;
        float sv = sF[off];
        float o = (1.f - z) * n + z * sv;
        if (writeF32) outF[off] = o;
        else          outBf[off] = f2bf(o);
      }
    }
  }
}

extern "C" void kernel_launch(void* const* d_in, const int* in_sizes, int n_in,
                              void* d_out, int out_size, void* d_ws, size_t ws_size,
                              hipStream_t stream) {
  const float* x    = (const float*)d_in[0];
  const int*   par  = (const int*)d_in[1];
  const int*   chd  = (const int*)d_in[2];
  const int*   cnt  = (const int*)d_in[3];
  const float* Wres = (const float*)d_in[4];
  const float* bres = (const float*)d_in[5];
  const float* Wpar = (const float*)d_in[6];
  const float* bpar = (const float*)d_in[7];
  const float* Wnbr = (const float*)d_in[8];
  const float* bnbr = (const float*)d_in[9];
  const float* Wih  = (const float*)d_in[10];
  const float* Whh  = (const float*)d_in[11];
  const float* bih  = (const float*)d_in[12];
  const float* bhh  = (const float*)d_in[13];

  char* ws = (char*)d_ws;
  size_t off = 0;
  auto alloc = [&](size_t sz) { char* p = ws + off; off += (sz + 255) & ~(size_t)255; return p; };
  us*    Wg   = (us*)alloc((size_t)1024 * 512 * 2);
  us*    Wcat = (us*)alloc((size_t)256 * 512 * 2);
  us*    Wr   = (us*)alloc((size_t)256 * 256 * 2);
  float* bcat = (float*)alloc(256 * 4);
  float* bg   = (float*)alloc(1024 * 4);
  us*    xbf  = (us*)alloc((size_t)MM * 256 * 2);  // reused as s_bf after resize
  us*    h0   = (us*)alloc((size_t)MM * 256 * 2);
  us*    h1   = (us*)alloc((size_t)MM * 256 * 2);
  us*    Acat = (us*)alloc((size_t)MM * 512 * 2);
  us*    sbf  = xbf;
  float* sF   = (float*)d_out;  // s_f32 scratch lives in d_out (overwritten at end)

  k_prep<<<256, 256, 0, stream>>>(Wres, Wpar, bpar, Wnbr, bnbr, Wih, Whh, bih, bhh,
                                  Wr, Wcat, bcat, Wg, bg);
  k_f2bf<<<(MM * 256 / 8) / 256, 256, 0, stream>>>(x, xbf, MM * 256 / 8);

  // h0 = x @ W_resize^T + b_resize
  k_gemm<0><<<(MM / 128) * 2, 256, 0, stream>>>(
      xbf, xbf, 256, 256, Wr, 256, bres, h0, nullptr, nullptr, 0, 2);

  us* hc = h0;
  for (int it = 0; it < 3; ++it) {
    us* hn = (hc == h0) ? h1 : h0;
    k_gather<<<MM / 4, 256, 0, stream>>>(hc, par, chd, cnt, Acat);
    // s = [p|m] @ Wcat^T + bcat  -> s_bf + s_f32(in d_out)
    k_gemm<1><<<(MM / 128) * 2, 256, 0, stream>>>(
        Acat, Acat, 512, 512, Wcat, 512, bcat, sbf, sF, nullptr, 0, 2);
    // fused GRU: [h|s] @ Wg^T, gate epilogue -> h_next (bf16) or d_out (f32, last)
    k_gemm<2><<<(MM / 128) * 8, 256, 0, stream>>>(
        hc, sbf, 256, 256, Wg, 512, bg, hn, (float*)d_out, sF, (it == 2) ? 1 : 0, 8);
    hc = hn;
  }
}

// Round 5
// 558.929 us; speedup vs baseline: 3.5673x; 1.1041x over previous
//
#include <hip/hip_runtime.h>

typedef unsigned short us;
typedef us us4 __attribute__((ext_vector_type(4)));
typedef us us8 __attribute__((ext_vector_type(8)));
typedef short bf16x8 __attribute__((ext_vector_type(8)));
typedef float f32x4 __attribute__((ext_vector_type(4)));

#define DEVI static __device__ __forceinline__

// constants for this problem instance
#define BB 16
#define NN 4096
#define PP 256
#define CC 8
#define MM (BB * NN)   // 65536

DEVI float bf2f(us u) { unsigned x = ((unsigned)u) << 16; return __builtin_bit_cast(float, x); }
DEVI us f2bf(float f) {
  unsigned x = __builtin_bit_cast(unsigned, f);
  x += 0x7fffu + ((x >> 16) & 1u);   // round to nearest even
  return (us)(x >> 16);
}

DEVI void gload_lds16(const void* g, void* l) {
  __builtin_amdgcn_global_load_lds(
      (const __attribute__((address_space(1))) void*)g,
      (__attribute__((address_space(3))) void*)l, 16, 0, 0);
}

DEVI float sigf(float x) { return 1.f / (1.f + __expf(-x)); }
DEVI float tanhfast(float a) {
  float aa = fabsf(a);
  float t = 1.f - 2.f / (1.f + __expf(2.f * aa));
  return copysignf(t, a);
}

// ---------------- weight prep: fp32 -> bf16, concatenated / gate-interleaved ----
// Wg layout (shuffle-free): row R -> J16 = R>>6, gate g = (R>>4)&3, c = R&15,
// output col j = J16*16 + c. Over K=512 ([h | s]):
//   g=0 (r):  [W_ih_r | W_hh_r]   g=1 (z): [W_ih_z | W_hh_z]
//   g=2 (xn): [W_ih_n | 0]        g=3 (hn): [0 | W_hh_n]
__global__ void k_prep(const float* __restrict__ Wres,
                       const float* __restrict__ Wpar, const float* __restrict__ bpar,
                       const float* __restrict__ Wnbr, const float* __restrict__ bnbr,
                       const float* __restrict__ Wih, const float* __restrict__ Whh,
                       const float* __restrict__ bih, const float* __restrict__ bhh,
                       us* __restrict__ Wr, us* __restrict__ Wcat, float* __restrict__ bcat,
                       us* __restrict__ Wg, float* __restrict__ bg) {
  int tid = blockIdx.x * blockDim.x + threadIdx.x;
  int nth = gridDim.x * blockDim.x;
  for (int i = tid; i < 256 * 256; i += nth) Wr[i] = f2bf(Wres[i]);
  for (int i = tid; i < 256 * 512; i += nth) {
    int o = i >> 9, k = i & 511;
    float v = (k < 256) ? Wpar[o * 256 + k] : Wnbr[o * 256 + (k - 256)];
    Wcat[i] = f2bf(v);
  }
  for (int i = tid; i < 256; i += nth) bcat[i] = bpar[i] + bnbr[i];
  for (int i = tid; i < 1024 * 512; i += nth) {
    int R = i >> 9, k = i & 511;
    int g = (R >> 4) & 3, j = ((R >> 6) << 4) + (R & 15);
    float v = 0.f;
    if (g == 0)      v = (k < 256) ? Wih[j * 256 + k]         : Whh[j * 256 + (k - 256)];
    else if (g == 1) v = (k < 256) ? Wih[(256 + j) * 256 + k] : Whh[(256 + j) * 256 + (k - 256)];
    else if (g == 2) v = (k < 256) ? Wih[(512 + j) * 256 + k] : 0.f;
    else             v = (k < 256) ? 0.f                      : Whh[(512 + j) * 256 + (k - 256)];
    Wg[i] = f2bf(v);
  }
  for (int i = tid; i < 1024; i += nth) {
    int g = (i >> 4) & 3, j = ((i >> 6) << 4) + (i & 15);
    float v;
    if (g == 0)      v = bih[j] + bhh[j];
    else if (g == 1) v = bih[256 + j] + bhh[256 + j];
    else if (g == 2) v = bih[512 + j];
    else             v = bhh[512 + j];
    bg[i] = v;
  }
}

// ---------------- x fp32 -> bf16 (vectorized) ----------------
__global__ __launch_bounds__(256) void k_f2bf(const float* __restrict__ x,
                                              us* __restrict__ o, int n8) {
  int i = blockIdx.x * blockDim.x + threadIdx.x;
  if (i >= n8) return;
  const float4* p = (const float4*)x + (size_t)i * 2;
  float4 a = p[0], b = p[1];
  us8 r;
  r[0] = f2bf(a.x); r[1] = f2bf(a.y); r[2] = f2bf(a.z); r[3] = f2bf(a.w);
  r[4] = f2bf(b.x); r[5] = f2bf(b.y); r[6] = f2bf(b.z); r[7] = f2bf(b.w);
  *(us8*)(o + (size_t)i * 8) = r;
}

// ---------------- gather: A_cat = [h[parent] | avg children h] (bf16) ----------
// All 8 child rows loaded unconditionally (indices always valid) so the loads
// issue in one latency window; contribution masked by count.
__global__ __launch_bounds__(256)
void k_gather(const us* __restrict__ h, const int* __restrict__ par,
              const int* __restrict__ chd, const int* __restrict__ cnt,
              us* __restrict__ Acat) {
  int wid = (blockIdx.x * blockDim.x + threadIdx.x) >> 6;  // one wave per node
  int l = threadIdx.x & 63;
  int m = wid;                       // 0..MM-1
  int b = m >> 12;                   // N = 4096
  int rowP = (b << 12) + par[m];
  us4 pv = *((const us4*)(h + ((size_t)rowP << 8)) + l);
  *((us4*)(Acat + ((size_t)m << 9)) + l) = pv;
  int c = cnt[m];
  float inv = 1.f / (float)c;
  const int* ch = chd + (size_t)m * CC;
  us4 cv[CC];
#pragma unroll
  for (int i = 0; i < CC; ++i) {
    int rowC = (b << 12) + ch[i];
    cv[i] = *((const us4*)(h + ((size_t)rowC << 8)) + l);
  }
  float a0 = 0.f, a1 = 0.f, a2 = 0.f, a3 = 0.f;
#pragma unroll
  for (int i = 0; i < CC; ++i) {
    float wgt = (i < c) ? 1.f : 0.f;
    a0 += wgt * bf2f(cv[i][0]); a1 += wgt * bf2f(cv[i][1]);
    a2 += wgt * bf2f(cv[i][2]); a3 += wgt * bf2f(cv[i][3]);
  }
  us4 nb;
  nb[0] = f2bf(a0 * inv); nb[1] = f2bf(a1 * inv);
  nb[2] = f2bf(a2 * inv); nb[3] = f2bf(a3 * inv);
  *((us4*)(Acat + ((size_t)m << 9) + 256) + l) = nb;
}

// ---------------- MFMA K-step (256x256 tile) with compile-time j-mask ----------
// 8 waves as 2(M) x 4(N); per wave 128x64 output = acc[8][4].
template <int JM>
DEVI void mma8(const us* As, const us* Bs, int wr, int wc, int l,
               f32x4 (&acc)[8][4]) {
#pragma unroll
  for (int ks = 0; ks < 2; ++ks) {
    bf16x8 af[8], bfr[4];
#pragma unroll
    for (int i = 0; i < 8; ++i) {
      int row = wr * 128 + i * 16 + (l & 15);
      int kb = ((ks * 32 + (l >> 4) * 8) * 2) ^ ((row & 7) << 4);  // swizzled read
      af[i] = *(const bf16x8*)((const char*)As + row * 128 + kb);
    }
#pragma unroll
    for (int j = 0; j < 4; ++j)
      if (JM & (1 << j)) {
        int row = wc * 64 + j * 16 + (l & 15);
        int kb = ((ks * 32 + (l >> 4) * 8) * 2) ^ ((row & 7) << 4);
        bfr[j] = *(const bf16x8*)((const char*)Bs + row * 128 + kb);
      }
#pragma unroll
    for (int i = 0; i < 8; ++i)
#pragma unroll
      for (int j = 0; j < 4; ++j)
        if (JM & (1 << j))
          acc[i][j] = __builtin_amdgcn_mfma_f32_16x16x32_bf16(af[i], bfr[j], acc[i][j], 0, 0, 0);
  }
}

// ---------------- GEMM: C = A @ Bw^T (+bias), 256x256 tile, dbuf prefetch ------
// Compile-time KTOT/KSPLIT/NT -> fully unrolled K-loop (A-concat switch and
// gate-mask select resolved at compile time; staging addrs strength-reduced).
// Flat grid XCD-chunked (grid%8==0): A-panel sharers run back-to-back per XCD.
// K-loop: stage(next) -> vmcnt(8) counted -> barrier -> MFMA -> barrier.
// LDS 128 KB (2x(32+32) KB), 1 block/CU, 8 waves (2/SIMD), reg budget 256.
// NOTE: never request >2 waves/SIMD here — acc alone is 128 regs; at 4/SIMD
// (128-reg budget) the R2 experiment spilled: 2.4 GB/dispatch scratch, 3x slow.
template <int EPI, int KTOT, int KSPLIT, int NT>
__global__ __launch_bounds__(512, 2)
void k_gemm(const us* __restrict__ A0, const us* __restrict__ A1, int strideA,
            const us* __restrict__ Bw, const float* __restrict__ bias,
            us* __restrict__ outBf, float* __restrict__ outF,
            const float* __restrict__ sF, int writeF32) {
  __shared__ __align__(16) us As[2][256 * 64];
  __shared__ __align__(16) us Bs[2][256 * 64];
  int tid = threadIdx.x;
  int w = tid >> 6, l = tid & 63;
  int wr = w >> 2, wc = w & 3;
  int bid = blockIdx.x;
  int per = gridDim.x >> 3;
  int g = (bid & 7) * per + (bid >> 3);
  int mi, ni;
  if (NT == 1) { mi = g; ni = 0; }
  else         { mi = g / NT; ni = g - mi * NT; }
  int mBase = mi * 256, nBase = ni * 256;
  f32x4 acc[8][4] = {};

  auto stage = [&](int t) {
    int kt = t * 64, buf = t & 1;
    const us* aSrc; int kOff;
    if (kt < KSPLIT) { aSrc = A0; kOff = kt; }
    else             { aSrc = A1; kOff = kt - KSPLIT; }
#pragma unroll
    for (int c = 0; c < 4; ++c) {
      int row = c * 64 + (tid >> 3);
      int kb = ((tid & 7) * 16) ^ ((row & 7) << 4);   // pre-swizzled global source
      const char* ga = (const char*)(aSrc + (size_t)(mBase + row) * strideA + kOff) + kb;
      gload_lds16(ga, (char*)As[buf] + row * 128 + (tid & 7) * 16);
      const char* gb = (const char*)(Bw + (size_t)(nBase + row) * KTOT + kt) + kb;
      gload_lds16(gb, (char*)Bs[buf] + row * 128 + (tid & 7) * 16);
    }
  };

  constexpr int NKT = KTOT / 64;
  stage(0);
#pragma unroll
  for (int t = 0; t < NKT; ++t) {
    if (t + 1 < NKT) {
      stage(t + 1);
      asm volatile("s_waitcnt vmcnt(8)" ::: "memory");  // this tile's 8 loads done
    } else {
      asm volatile("s_waitcnt vmcnt(0)" ::: "memory");
    }
    __syncthreads();
    int buf = t & 1;
    if (EPI == 2) {
      if (t * 64 < KSPLIT) mma8<0b0111>(As[buf], Bs[buf], wr, wc, l, acc);  // skip hn
      else                 mma8<0b1011>(As[buf], Bs[buf], wr, wc, l, acc);  // skip xn
    } else {
      mma8<0b1111>(As[buf], Bs[buf], wr, wc, l, acc);
    }
    __syncthreads();   // all waves done with buf before it is re-staged
  }

  int rBase0 = mBase + wr * 128;
  int cBase0 = nBase + wc * 64;
  if (EPI == 0 || EPI == 1) {
#pragma unroll
    for (int i = 0; i < 8; ++i)
#pragma unroll
      for (int j = 0; j < 4; ++j) {
        int col = cBase0 + j * 16 + (l & 15);
        int row0 = rBase0 + i * 16 + ((l >> 4) << 2);
        float bb = bias[col];
#pragma unroll
        for (int e = 0; e < 4; ++e) {
          float v = acc[i][j][e] + bb;
          size_t off = (size_t)(row0 + e) * 256 + col;
          outBf[off] = f2bf(v);
          if (EPI == 1) outF[off] = v;
        }
      }
  } else {
    // shuffle-free: j-fragment == gate (wave spans 64 gate-cols = 16 out cols)
    int outCol = ((nBase >> 6) + wc) * 16 + (l & 15);
    float b0 = bias[cBase0 + 0  + (l & 15)];
    float b1 = bias[cBase0 + 16 + (l & 15)];
    float b2 = bias[cBase0 + 32 + (l & 15)];
    float b3 = bias[cBase0 + 48 + (l & 15)];
#pragma unroll
    for (int i = 0; i < 8; ++i) {
      int row0 = rBase0 + i * 16 + ((l >> 4) << 2);
#pragma unroll
      for (int e = 0; e < 4; ++e) {
        float r = sigf(acc[i][0][e] + b0);
        float z = sigf(acc[i][1][e] + b1);
        float n = tanhfast(acc[i][2][e] + b2 + r * (acc[i][3][e] + b3));
        size_t off = (size_t)(row0 + e) * 256 + outCol;
        float sv = sF[off];
        float o = (1.f - z) * n + z * sv;
        if (writeF32) outF[off] = o;
        else          outBf[off] = f2bf(o);
      }
    }
  }
}

extern "C" void kernel_launch(void* const* d_in, const int* in_sizes, int n_in,
                              void* d_out, int out_size, void* d_ws, size_t ws_size,
                              hipStream_t stream) {
  const float* x    = (const float*)d_in[0];
  const int*   par  = (const int*)d_in[1];
  const int*   chd  = (const int*)d_in[2];
  const int*   cnt  = (const int*)d_in[3];
  const float* Wres = (const float*)d_in[4];
  const float* bres = (const float*)d_in[5];
  const float* Wpar = (const float*)d_in[6];
  const float* bpar = (const float*)d_in[7];
  const float* Wnbr = (const float*)d_in[8];
  const float* bnbr = (const float*)d_in[9];
  const float* Wih  = (const float*)d_in[10];
  const float* Whh  = (const float*)d_in[11];
  const float* bih  = (const float*)d_in[12];
  const float* bhh  = (const float*)d_in[13];

  char* ws = (char*)d_ws;
  size_t off = 0;
  auto alloc = [&](size_t sz) { char* p = ws + off; off += (sz + 255) & ~(size_t)255; return p; };
  us*    Wg   = (us*)alloc((size_t)1024 * 512 * 2);
  us*    Wcat = (us*)alloc((size_t)256 * 512 * 2);
  us*    Wr   = (us*)alloc((size_t)256 * 256 * 2);
  float* bcat = (float*)alloc(256 * 4);
  float* bg   = (float*)alloc(1024 * 4);
  us*    xbf  = (us*)alloc((size_t)MM * 256 * 2);  // reused as s_bf after resize
  us*    h0   = (us*)alloc((size_t)MM * 256 * 2);
  us*    h1   = (us*)alloc((size_t)MM * 256 * 2);
  us*    Acat = (us*)alloc((size_t)MM * 512 * 2);
  us*    sbf  = xbf;
  float* sF   = (float*)d_out;  // s_f32 scratch lives in d_out (overwritten at end)

  k_prep<<<256, 256, 0, stream>>>(Wres, Wpar, bpar, Wnbr, bnbr, Wih, Whh, bih, bhh,
                                  Wr, Wcat, bcat, Wg, bg);
  k_f2bf<<<(MM * 256 / 8) / 256, 256, 0, stream>>>(x, xbf, MM * 256 / 8);

  // h0 = x @ W_resize^T + b_resize   (M/256 = 256 blocks, single n-tile)
  k_gemm<0, 256, 256, 1><<<256, 512, 0, stream>>>(
      xbf, xbf, 256, Wr, bres, h0, nullptr, nullptr, 0);

  us* hc = h0;
  for (int it = 0; it < 3; ++it) {
    us* hn = (hc == h0) ? h1 : h0;
    k_gather<<<MM / 4, 256, 0, stream>>>(hc, par, chd, cnt, Acat);
    // s = [p|m] @ Wcat^T + bcat  -> s_bf + s_f32(in d_out)
    k_gemm<1, 512, 512, 1><<<256, 512, 0, stream>>>(
        Acat, Acat, 512, Wcat, bcat, sbf, sF, nullptr, 0);
    // fused GRU: [h|s] @ Wg^T, gate epilogue -> h_next (bf16) or d_out (f32, last)
    k_gemm<2, 512, 256, 4><<<1024, 512, 0, stream>>>(
        hc, sbf, 256, Wg, bg, hn, (float*)d_out, sF, (it == 2) ? 1 : 0);
    hc = hn;
  }
}

// Round 6
// 536.089 us; speedup vs baseline: 3.7193x; 1.0426x over previous
//
#include <hip/hip_runtime.h>

typedef unsigned short us;
typedef us us4 __attribute__((ext_vector_type(4)));
typedef us us8 __attribute__((ext_vector_type(8)));
typedef short bf16x8 __attribute__((ext_vector_type(8)));
typedef float f32x4 __attribute__((ext_vector_type(4)));

#define DEVI static __device__ __forceinline__

// constants for this problem instance
#define BB 16
#define NN 4096
#define PP 256
#define CC 8
#define MM (BB * NN)   // 65536

DEVI float bf2f(us u) { unsigned x = ((unsigned)u) << 16; return __builtin_bit_cast(float, x); }
DEVI us f2bf(float f) {
  unsigned x = __builtin_bit_cast(unsigned, f);
  x += 0x7fffu + ((x >> 16) & 1u);   // round to nearest even
  return (us)(x >> 16);
}

DEVI void gload_lds16(const void* g, void* l) {
  __builtin_amdgcn_global_load_lds(
      (const __attribute__((address_space(1))) void*)g,
      (__attribute__((address_space(3))) void*)l, 16, 0, 0);
}

DEVI float sigf(float x) { return 1.f / (1.f + __expf(-x)); }
DEVI float tanhfast(float a) {
  float aa = fabsf(a);
  float t = 1.f - 2.f / (1.f + __expf(2.f * aa));
  return copysignf(t, a);
}

// ---------------- weight prep: fp32 -> bf16, concatenated / gate-interleaved ----
// Wg layout (shuffle-free): row R -> J16 = R>>6, gate g = (R>>4)&3, c = R&15,
// output col j = J16*16 + c. Over K=512 ([h | s]):
//   g=0 (r):  [W_ih_r | W_hh_r]   g=1 (z): [W_ih_z | W_hh_z]
//   g=2 (xn): [W_ih_n | 0]        g=3 (hn): [0 | W_hh_n]
__global__ void k_prep(const float* __restrict__ Wres,
                       const float* __restrict__ Wpar, const float* __restrict__ bpar,
                       const float* __restrict__ Wnbr, const float* __restrict__ bnbr,
                       const float* __restrict__ Wih, const float* __restrict__ Whh,
                       const float* __restrict__ bih, const float* __restrict__ bhh,
                       us* __restrict__ Wr, us* __restrict__ Wcat, float* __restrict__ bcat,
                       us* __restrict__ Wg, float* __restrict__ bg) {
  int tid = blockIdx.x * blockDim.x + threadIdx.x;
  int nth = gridDim.x * blockDim.x;
  for (int i = tid; i < 256 * 256; i += nth) Wr[i] = f2bf(Wres[i]);
  for (int i = tid; i < 256 * 512; i += nth) {
    int o = i >> 9, k = i & 511;
    float v = (k < 256) ? Wpar[o * 256 + k] : Wnbr[o * 256 + (k - 256)];
    Wcat[i] = f2bf(v);
  }
  for (int i = tid; i < 256; i += nth) bcat[i] = bpar[i] + bnbr[i];
  for (int i = tid; i < 1024 * 512; i += nth) {
    int R = i >> 9, k = i & 511;
    int g = (R >> 4) & 3, j = ((R >> 6) << 4) + (R & 15);
    float v = 0.f;
    if (g == 0)      v = (k < 256) ? Wih[j * 256 + k]         : Whh[j * 256 + (k - 256)];
    else if (g == 1) v = (k < 256) ? Wih[(256 + j) * 256 + k] : Whh[(256 + j) * 256 + (k - 256)];
    else if (g == 2) v = (k < 256) ? Wih[(512 + j) * 256 + k] : 0.f;
    else             v = (k < 256) ? 0.f                      : Whh[(512 + j) * 256 + (k - 256)];
    Wg[i] = f2bf(v);
  }
  for (int i = tid; i < 1024; i += nth) {
    int g = (i >> 4) & 3, j = ((i >> 6) << 4) + (i & 15);
    float v;
    if (g == 0)      v = bih[j] + bhh[j];
    else if (g == 1) v = bih[256 + j] + bhh[256 + j];
    else if (g == 2) v = bih[512 + j];
    else             v = bhh[512 + j];
    bg[i] = v;
  }
}

// ---------------- x fp32 -> bf16 (vectorized) ----------------
__global__ __launch_bounds__(256) void k_f2bf(const float* __restrict__ x,
                                              us* __restrict__ o, int n8) {
  int i = blockIdx.x * blockDim.x + threadIdx.x;
  if (i >= n8) return;
  const float4* p = (const float4*)x + (size_t)i * 2;
  float4 a = p[0], b = p[1];
  us8 r;
  r[0] = f2bf(a.x); r[1] = f2bf(a.y); r[2] = f2bf(a.z); r[3] = f2bf(a.w);
  r[4] = f2bf(b.x); r[5] = f2bf(b.y); r[6] = f2bf(b.z); r[7] = f2bf(b.w);
  *(us8*)(o + (size_t)i * 8) = r;
}

// ---------------- gather: A_cat = [h[parent] | avg children h] (bf16) ----------
// All 8 child rows loaded unconditionally (indices always valid) so the loads
// issue in one latency window; contribution masked by count.
__global__ __launch_bounds__(256)
void k_gather(const us* __restrict__ h, const int* __restrict__ par,
              const int* __restrict__ chd, const int* __restrict__ cnt,
              us* __restrict__ Acat) {
  int wid = (blockIdx.x * blockDim.x + threadIdx.x) >> 6;  // one wave per node
  int l = threadIdx.x & 63;
  int m = wid;                       // 0..MM-1
  int b = m >> 12;                   // N = 4096
  int rowP = (b << 12) + par[m];
  us4 pv = *((const us4*)(h + ((size_t)rowP << 8)) + l);
  *((us4*)(Acat + ((size_t)m << 9)) + l) = pv;
  int c = cnt[m];
  float inv = 1.f / (float)c;
  const int* ch = chd + (size_t)m * CC;
  us4 cv[CC];
#pragma unroll
  for (int i = 0; i < CC; ++i) {
    int rowC = (b << 12) + ch[i];
    cv[i] = *((const us4*)(h + ((size_t)rowC << 8)) + l);
  }
  float a0 = 0.f, a1 = 0.f, a2 = 0.f, a3 = 0.f;
#pragma unroll
  for (int i = 0; i < CC; ++i) {
    float wgt = (i < c) ? 1.f : 0.f;
    a0 += wgt * bf2f(cv[i][0]); a1 += wgt * bf2f(cv[i][1]);
    a2 += wgt * bf2f(cv[i][2]); a3 += wgt * bf2f(cv[i][3]);
  }
  us4 nb;
  nb[0] = f2bf(a0 * inv); nb[1] = f2bf(a1 * inv);
  nb[2] = f2bf(a2 * inv); nb[3] = f2bf(a3 * inv);
  *((us4*)(Acat + ((size_t)m << 9) + 256) + l) = nb;
}

// ---------------- MFMA K-step (256x256 tile) with compile-time j-mask ----------
// 8 waves as 2(M) x 4(N); per wave 128x64 output = acc[8][4].
template <int JM>
DEVI void mma8(const us* As, const us* Bs, int wr, int wc, int l,
               f32x4 (&acc)[8][4]) {
#pragma unroll
  for (int ks = 0; ks < 2; ++ks) {
    bf16x8 af[8], bfr[4];
#pragma unroll
    for (int i = 0; i < 8; ++i) {
      int row = wr * 128 + i * 16 + (l & 15);
      int kb = ((ks * 32 + (l >> 4) * 8) * 2) ^ ((row & 7) << 4);  // swizzled read
      af[i] = *(const bf16x8*)((const char*)As + row * 128 + kb);
    }
#pragma unroll
    for (int j = 0; j < 4; ++j)
      if (JM & (1 << j)) {
        int row = wc * 64 + j * 16 + (l & 15);
        int kb = ((ks * 32 + (l >> 4) * 8) * 2) ^ ((row & 7) << 4);
        bfr[j] = *(const bf16x8*)((const char*)Bs + row * 128 + kb);
      }
#pragma unroll
    for (int i = 0; i < 8; ++i)
#pragma unroll
      for (int j = 0; j < 4; ++j)
        if (JM & (1 << j))
          acc[i][j] = __builtin_amdgcn_mfma_f32_16x16x32_bf16(af[i], bfr[j], acc[i][j], 0, 0, 0);
  }
}

DEVI void raw_barrier() {
  __builtin_amdgcn_sched_barrier(0);
  __builtin_amdgcn_s_barrier();      // RAW barrier: no implicit vmcnt(0) drain
  __builtin_amdgcn_sched_barrier(0);
}

// ---------------- GEMM: C = A @ Bw^T (+bias), 256x256 tile, dbuf prefetch ------
// Compile-time KTOT/KSPLIT/NT -> fully unrolled K-loop. XCD-chunked flat grid.
// K-loop (T3/T4 counted-vmcnt pipeline, m201 lineage):
//   stage(t+1) -> s_waitcnt vmcnt(8) (tile t's loads done; t+1's 8 stay IN
//   FLIGHT) -> raw s_barrier -> MFMA(tile t) -> raw s_barrier.
// CRITICAL: must use __builtin_amdgcn_s_barrier(), NOT __syncthreads() —
// __syncthreads makes the compiler emit s_waitcnt vmcnt(0) before s_barrier,
// draining the prefetch queue every tile (measured R5: 110 µs vs ~25 µs floor).
// Race safety: barrier1 after per-wave vmcnt(8) => all waves' tile-t LDS
// writes visible; barrier2 after lgkm-gated MFMA reads => buf safe to restage
// at t+2. Prefetched loads legally cross both raw barriers.
// NOTE: never request >2 waves/SIMD here — acc alone is 128 regs; at 4/SIMD
// (128-reg budget) the R2 experiment spilled: 2.4 GB/dispatch scratch, 3x slow.
template <int EPI, int KTOT, int KSPLIT, int NT>
__global__ __launch_bounds__(512, 2)
void k_gemm(const us* __restrict__ A0, const us* __restrict__ A1, int strideA,
            const us* __restrict__ Bw, const float* __restrict__ bias,
            us* __restrict__ outBf, float* __restrict__ outF,
            const float* __restrict__ sF, int writeF32) {
  __shared__ __align__(16) us As[2][256 * 64];
  __shared__ __align__(16) us Bs[2][256 * 64];
  int tid = threadIdx.x;
  int w = tid >> 6, l = tid & 63;
  int wr = w >> 2, wc = w & 3;
  int bid = blockIdx.x;
  int per = gridDim.x >> 3;
  int g = (bid & 7) * per + (bid >> 3);
  int mi, ni;
  if (NT == 1) { mi = g; ni = 0; }
  else         { mi = g / NT; ni = g - mi * NT; }
  int mBase = mi * 256, nBase = ni * 256;
  f32x4 acc[8][4] = {};

  auto stage = [&](int t) {
    int kt = t * 64, buf = t & 1;
    const us* aSrc; int kOff;
    if (kt < KSPLIT) { aSrc = A0; kOff = kt; }
    else             { aSrc = A1; kOff = kt - KSPLIT; }
#pragma unroll
    for (int c = 0; c < 4; ++c) {
      int row = c * 64 + (tid >> 3);
      int kb = ((tid & 7) * 16) ^ ((row & 7) << 4);   // pre-swizzled global source
      const char* ga = (const char*)(aSrc + (size_t)(mBase + row) * strideA + kOff) + kb;
      gload_lds16(ga, (char*)As[buf] + row * 128 + (tid & 7) * 16);
      const char* gb = (const char*)(Bw + (size_t)(nBase + row) * KTOT + kt) + kb;
      gload_lds16(gb, (char*)Bs[buf] + row * 128 + (tid & 7) * 16);
    }
  };

  constexpr int NKT = KTOT / 64;
  stage(0);
#pragma unroll
  for (int t = 0; t < NKT; ++t) {
    if (t + 1 < NKT) {
      stage(t + 1);
      asm volatile("s_waitcnt vmcnt(8)" ::: "memory");  // tile t done; t+1 in flight
    } else {
      asm volatile("s_waitcnt vmcnt(0)" ::: "memory");
    }
    raw_barrier();                     // LDS tile-t writes visible to all waves
    int buf = t & 1;
    if (EPI == 2) {
      if (t * 64 < KSPLIT) mma8<0b0111>(As[buf], Bs[buf], wr, wc, l, acc);  // skip hn
      else                 mma8<0b1011>(As[buf], Bs[buf], wr, wc, l, acc);  // skip xn
    } else {
      mma8<0b1111>(As[buf], Bs[buf], wr, wc, l, acc);
    }
    raw_barrier();                     // all reads of buf done before restage
  }

  int rBase0 = mBase + wr * 128;
  int cBase0 = nBase + wc * 64;
  if (EPI == 0 || EPI == 1) {
#pragma unroll
    for (int i = 0; i < 8; ++i)
#pragma unroll
      for (int j = 0; j < 4; ++j) {
        int col = cBase0 + j * 16 + (l & 15);
        int row0 = rBase0 + i * 16 + ((l >> 4) << 2);
        float bb = bias[col];
#pragma unroll
        for (int e = 0; e < 4; ++e) {
          float v = acc[i][j][e] + bb;
          size_t off = (size_t)(row0 + e) * 256 + col;
          outBf[off] = f2bf(v);
          if (EPI == 1) outF[off] = v;
        }
      }
  } else {
    // shuffle-free: j-fragment == gate (wave spans 64 gate-cols = 16 out cols)
    int outCol = ((nBase >> 6) + wc) * 16 + (l & 15);
    float b0 = bias[cBase0 + 0  + (l & 15)];
    float b1 = bias[cBase0 + 16 + (l & 15)];
    float b2 = bias[cBase0 + 32 + (l & 15)];
    float b3 = bias[cBase0 + 48 + (l & 15)];
#pragma unroll
    for (int i = 0; i < 8; ++i) {
      int row0 = rBase0 + i * 16 + ((l >> 4) << 2);
#pragma unroll
      for (int e = 0; e < 4; ++e) {
        float r = sigf(acc[i][0][e] + b0);
        float z = sigf(acc[i][1][e] + b1);
        float n = tanhfast(acc[i][2][e] + b2 + r * (acc[i][3][e] + b3));
        size_t off = (size_t)(row0 + e) * 256 + outCol;
        float sv = sF[off];
        float o = (1.f - z) * n + z * sv;
        if (writeF32) outF[off] = o;
        else          outBf[off] = f2bf(o);
      }
    }
  }
}

extern "C" void kernel_launch(void* const* d_in, const int* in_sizes, int n_in,
                              void* d_out, int out_size, void* d_ws, size_t ws_size,
                              hipStream_t stream) {
  const float* x    = (const float*)d_in[0];
  const int*   par  = (const int*)d_in[1];
  const int*   chd  = (const int*)d_in[2];
  const int*   cnt  = (const int*)d_in[3];
  const float* Wres = (const float*)d_in[4];
  const float* bres = (const float*)d_in[5];
  const float* Wpar = (const float*)d_in[6];
  const float* bpar = (const float*)d_in[7];
  const float* Wnbr = (const float*)d_in[8];
  const float* bnbr = (const float*)d_in[9];
  const float* Wih  = (const float*)d_in[10];
  const float* Whh  = (const float*)d_in[11];
  const float* bih  = (const float*)d_in[12];
  const float* bhh  = (const float*)d_in[13];

  char* ws = (char*)d_ws;
  size_t off = 0;
  auto alloc = [&](size_t sz) { char* p = ws + off; off += (sz + 255) & ~(size_t)255; return p; };
  us*    Wg   = (us*)alloc((size_t)1024 * 512 * 2);
  us*    Wcat = (us*)alloc((size_t)256 * 512 * 2);
  us*    Wr   = (us*)alloc((size_t)256 * 256 * 2);
  float* bcat = (float*)alloc(256 * 4);
  float* bg   = (float*)alloc(1024 * 4);
  us*    xbf  = (us*)alloc((size_t)MM * 256 * 2);  // reused as s_bf after resize
  us*    h0   = (us*)alloc((size_t)MM * 256 * 2);
  us*    h1   = (us*)alloc((size_t)MM * 256 * 2);
  us*    Acat = (us*)alloc((size_t)MM * 512 * 2);
  us*    sbf  = xbf;
  float* sF   = (float*)d_out;  // s_f32 scratch lives in d_out (overwritten at end)

  k_prep<<<256, 256, 0, stream>>>(Wres, Wpar, bpar, Wnbr, bnbr, Wih, Whh, bih, bhh,
                                  Wr, Wcat, bcat, Wg, bg);
  k_f2bf<<<(MM * 256 / 8) / 256, 256, 0, stream>>>(x, xbf, MM * 256 / 8);

  // h0 = x @ W_resize^T + b_resize   (M/256 = 256 blocks, single n-tile)
  k_gemm<0, 256, 256, 1><<<256, 512, 0, stream>>>(
      xbf, xbf, 256, Wr, bres, h0, nullptr, nullptr, 0);

  us* hc = h0;
  for (int it = 0; it < 3; ++it) {
    us* hn = (hc == h0) ? h1 : h0;
    k_gather<<<MM / 4, 256, 0, stream>>>(hc, par, chd, cnt, Acat);
    // s = [p|m] @ Wcat^T + bcat  -> s_bf + s_f32(in d_out)
    k_gemm<1, 512, 512, 1><<<256, 512, 0, stream>>>(
        Acat, Acat, 512, Wcat, bcat, sbf, sF, nullptr, 0);
    // fused GRU: [h|s] @ Wg^T, gate epilogue -> h_next (bf16) or d_out (f32, last)
    k_gemm<2, 512, 256, 4><<<1024, 512, 0, stream>>>(
        hc, sbf, 256, Wg, bg, hn, (float*)d_out, sF, (it == 2) ? 1 : 0);
    hc = hn;
  }
}